// Round 8
// baseline (248.906 us; speedup 1.0000x reference)
//
#include <hip/hip_runtime.h>

#define LPC_N 32
#define LPC_EPS 1e-5f
#define NREG 11                       // lags 0..10: register-resident
#define NLDS (LPC_N + 1 - NREG)       // lags 11..32: per-wave LDS (22 lags)

// R0-R7 matrix: tight budgets (caps 4-7 waves) => scratch spills or AGPR
// serialization; default budgets => allocator squeezes arch VGPRs below
// honest pressure and shadows/remats the arrays (VGPR_Count pinned at 36,
// per-access VALU overhead, mid-chain reload stalls, 90us plateau).
// Untested combination, this round:
//   (a) SMALL honest live set: lp[32] + ac[1..10] + ~12 temps ~= 55 regs
//       (lags 11..32 in per-wave LDS -- R4's twice-verified structure), AND
//   (b) GENEROUS budget: __launch_bounds__(256, 2) => 256-reg budget, 2.5x
//       honest need -- no pressure reason to shadow, remat, or spill.
//   (c) PLAIN stores (first A/B of the R0 nontemporal choice): output
//       (131 MB) fits in LLC beside the L3-resident input (~67 MB per
//       FETCH_SIZE); write-back lets L3 absorb the write stream instead of
//       forcing 131 MB through HBM inside the timed window each dispatch.
// LDS: 22 lags x 64 lanes x 4 B = 5.5 KB/wave, 22.5 KB/block -> 7 blocks/CU
// structural (28 waves/CU, 87%). [lag][lane] layout: bank = lane%32, 2-way
// = conflict-free; ds_read_b32 with imm offsets on the DS pipe.
__global__ __launch_bounds__(256, 2) void levinson_kernel(
    const float* __restrict__ pAC,   // [N+1, T]
    float* __restrict__ out,         // [N, T]
    int T)
{
    __shared__ float smem[4 * NLDS * 64];   // 22528 B/block, per-wave chunks

    const int tid  = threadIdx.x;
    const int lane = tid & 63;
    const int wv   = tid >> 6;
    const int t    = blockIdx.x * blockDim.x + tid;
    if (t >= T) return;

    float* wbuf = smem + wv * (NLDS * 64);

    // Stage cold lags into per-wave LDS (coalesced dword loads). Each lane
    // writes and reads only its own [lag][lane] column -> no barrier.
#pragma unroll
    for (int k = 0; k < NLDS; ++k) {
        float v = pAC[(size_t)(NREG + k) * T + t];
        wbuf[k * 64 + lane] = v;
    }

    // Hot lags -> registers (used 23..32x each).
    float ac[NREG];
#pragma unroll
    for (int k = 0; k < NREG; ++k)
        ac[k] = pAC[(size_t)k * T + t];

    // Fully unrolled => m is compile-time: folds to a VGPR read or a
    // ds_read_b32 with an immediate offset.
    auto AC = [&](int m) -> float {
        return (m < NREG) ? ac[m] : wbuf[(m - NREG) * 64 + lane];
    };

    float lp[LPC_N];
    float E = ac[0];

#pragma unroll
    for (int i = 0; i < LPC_N; ++i) {
        // rcp issued first: latency hides under the dot product.
        float invE = __builtin_amdgcn_rcpf(E);

        // acc = ac[i+1] + sum_{j<i} lp[j]*ac[i-j], two independent FMA chains.
        float s0 = AC(i + 1);
        float s1 = 0.0f;
#pragma unroll
        for (int j = 0; j + 1 < i; j += 2) {
            s0 += lp[j]     * AC(i - j);
            s1 += lp[j + 1] * AC(i - j - 1);
        }
        if (i & 1) {                    // leftover j = i-1 when i is odd
            s0 += lp[i - 1] * ac[1];
        }
        float acc = s0 + s1;

        float ki = acc * invE;
        float c  = fmaxf(1.0f - ki * ki, LPC_EPS);
        E *= c;

        // lp[j] = lp[j] - ki*lp[i-1-j] from OLD lp: pairwise swap update.
#pragma unroll
        for (int j = 0; j < i - 1 - j; ++j) {
            float a = lp[j];
            float b = lp[i - 1 - j];
            lp[j]         = a - ki * b;
            lp[i - 1 - j] = b - ki * a;
        }
        if (i & 1) {
            int m = (i - 1) >> 1;       // self-paired middle element
            lp[m] = lp[m] - ki * lp[m];
        }
        lp[i] = -ki;
    }

    // Plain (write-back) coalesced stores: let L3 absorb the write stream.
#pragma unroll
    for (int i = 0; i < LPC_N; ++i) {
        out[(size_t)i * T + t] = lp[i];
    }
}

extern "C" void kernel_launch(void* const* d_in, const int* in_sizes, int n_in,
                              void* d_out, int out_size, void* d_ws, size_t ws_size,
                              hipStream_t stream)
{
    const float* pAC = (const float*)d_in[0];
    float* out = (float*)d_out;
    int T = in_sizes[0] / (LPC_N + 1);   // 1048576

    int block = 256;
    int grid = (T + block - 1) / block;  // 4096 blocks
    levinson_kernel<<<grid, block, 0, stream>>>(pAC, out, T);
}